// Round 10
// baseline (248.088 us; speedup 1.0000x reference)
//
#include <hip/hip_runtime.h>
#include <hip/hip_bf16.h>
#include <stdint.h>

typedef __attribute__((ext_vector_type(8))) short short8;
typedef __attribute__((ext_vector_type(4))) float floatx4;

#define DEVI __device__ __forceinline__
#define MFMA16(a, b, c) __builtin_amdgcn_mfma_f32_16x16x32_bf16((a), (b), (c), 0, 0, 0)
#define MFMA8(a, b, c)  __builtin_amdgcn_mfma_f32_16x16x32_fp8_fp8((a), (b), (c), 0, 0, 0)

DEVI unsigned short f2bf(float x) {
    union { float f; unsigned int u; } v; v.f = x;
    unsigned int r = v.u + 0x7FFFu + ((v.u >> 16) & 1u);
    return (unsigned short)(r >> 16);
}
DEVI float bf2f(unsigned short h) {
    union { unsigned int u; float f; } v; v.u = ((unsigned int)h) << 16;
    return v.f;
}
DEVI unsigned char f2fp8(float x) {   // OCP e4m3 via HW converter
    int c = __builtin_amdgcn_cvt_pk_fp8_f32(x, x, 0, false);
    return (unsigned char)(c & 0xFF);
}

// ---------------- cast / transpose prep kernels ----------------

__global__ void cast_f32_bf16(const float* __restrict__ in, unsigned short* __restrict__ out, int n4) {
    int i = blockIdx.x * blockDim.x + threadIdx.x;
    if (i < n4) {
        float4 v = ((const float4*)in)[i];
        ushort4 o;
        o.x = f2bf(v.x); o.y = f2bf(v.y); o.z = f2bf(v.z); o.w = f2bf(v.w);
        ((ushort4*)out)[i] = o;
    }
}

// Wt[n][k] = bf16(W[k][n]);  W is [K][N] row-major
__global__ void transpose_cast(const float* __restrict__ W, unsigned short* __restrict__ Wt, int K, int N) {
    int idx = blockIdx.x * blockDim.x + threadIdx.x;
    if (idx < K * N) {
        int k = idx / N, n = idx % N;
        Wt[n * K + k] = f2bf(W[idx]);
    }
}

// ---------------- in-place fp8 fragment packing ----------------
// K pack (fp8): frag (n16, s): lane l holds K[n16*16+(l&15)][s*32+(l>>4)*8+j], j=0..7,
// stored at byte offset ((n16*8+s)*512 + l*8). 64-key tile spans 16 KB -> in-place via LDS.
__global__ __launch_bounds__(256) void pack_k8(unsigned char* __restrict__ kb) {
    __shared__ unsigned char T[64][272];
    const int b = blockIdx.y, k0 = blockIdx.x * 64;
    unsigned char* base = kb + (size_t)b * 1048576 + (size_t)k0 * 256;
    const int tid = threadIdx.x;
    #pragma unroll
    for (int it = 0; it < 4; ++it) {
        int idx = tid + it * 256;            // 0..1023 x 16B
        int row = idx >> 4, col = (idx & 15) * 16;
        *(int4*)&T[row][col] = *(const int4*)&base[(size_t)row * 256 + col];
    }
    __syncthreads();
    const int w = tid >> 6, lane = tid & 63, l15 = lane & 15, quad = lane >> 4;
    #pragma unroll
    for (int s = 0; s < 8; ++s) {
        long o = *(const long*)&T[w * 16 + l15][s * 32 + quad * 8];
        *(long*)&base[(size_t)(w * 8 + s) * 512 + lane * 8] = o;
    }
}

// V pack (fp8): frag (nc, f16): lane l holds V[nc*32+(l>>4)*8+j][f16*16+(l&15)],
// stored at ((nc*16+f16)*512 + l*8). Same in-place property per 64-key tile.
__global__ __launch_bounds__(256) void pack_v8(unsigned char* __restrict__ vb) {
    __shared__ unsigned char T[64][272];
    const int b = blockIdx.y, k0 = blockIdx.x * 64;
    unsigned char* base = vb + (size_t)b * 1048576 + (size_t)k0 * 256;
    const int tid = threadIdx.x;
    #pragma unroll
    for (int it = 0; it < 4; ++it) {
        int idx = tid + it * 256;
        int row = idx >> 4, col = (idx & 15) * 16;
        *(int4*)&T[row][col] = *(const int4*)&base[(size_t)row * 256 + col];
    }
    __syncthreads();
    const int w = tid >> 6, lane = tid & 63, l15 = lane & 15, quad = lane >> 4;
    const int ncl = w >> 1;
    #pragma unroll
    for (int ff = 0; ff < 8; ++ff) {
        int f16 = (w & 1) * 8 + ff;
        union { unsigned char bts[8]; long l; } o;
        #pragma unroll
        for (int j = 0; j < 8; ++j)
            o.bts[j] = T[ncl * 32 + quad * 8 + j][f16 * 16 + l15];
        *(long*)&base[(size_t)(ncl * 16 + f16) * 512 + lane * 8] = o.l;
    }
}

// ---------------- bf16 MFMA GEMM: C = A @ Wt^T + bias (bf16 out) ----------------

template<int K>
__global__ __launch_bounds__(256) void gemm_bias(
    const unsigned short* __restrict__ A,
    const unsigned short* __restrict__ Wt,
    const float* __restrict__ bias,
    unsigned short* __restrict__ Cb,
    int M, int N)
{
    __shared__ unsigned short As[64][136];
    __shared__ unsigned short Bs[64][136];
    const int tid  = threadIdx.x;
    const int w    = tid >> 6;
    const int lane = tid & 63;
    const int quad = lane >> 4;
    const int l15  = lane & 15;
    const int m0 = blockIdx.x * 64;
    const int n0 = blockIdx.y * 64;

    floatx4 acc[4];
    #pragma unroll
    for (int t = 0; t < 4; ++t) acc[t] = (floatx4)0.0f;

    for (int kc = 0; kc < K; kc += 128) {
        __syncthreads();
        #pragma unroll
        for (int idx = tid; idx < 1024; idx += 256) {
            int r = idx >> 4, g = idx & 15;
            *(short8*)&As[r][g * 8] = *(const short8*)&A[(size_t)(m0 + r) * K + kc + g * 8];
            *(short8*)&Bs[r][g * 8] = *(const short8*)&Wt[(size_t)(n0 + r) * K + kc + g * 8];
        }
        __syncthreads();
        #pragma unroll
        for (int s = 0; s < 4; ++s) {
            short8 a = *(const short8*)&As[w * 16 + l15][s * 32 + quad * 8];
            #pragma unroll
            for (int t = 0; t < 4; ++t) {
                short8 bfr = *(const short8*)&Bs[t * 16 + l15][s * 32 + quad * 8];
                acc[t] = MFMA16(a, bfr, acc[t]);
            }
        }
    }

    #pragma unroll
    for (int t = 0; t < 4; ++t) {
        int n = n0 + t * 16 + l15;
        float bs = bias[n];
        #pragma unroll
        for (int r = 0; r < 4; ++r) {
            int m = m0 + w * 16 + quad * 4 + r;
            Cb[(size_t)m * N + n] = f2bf(acc[t][r] + bs);
        }
    }
}

// Fused Q/K/V GEMM with fp8 output: blockIdx.z selects weight/bias/output.
__global__ __launch_bounds__(256) void gemm_qkv(
    const unsigned short* __restrict__ A,
    const unsigned short* __restrict__ Wt0, const unsigned short* __restrict__ Wt1, const unsigned short* __restrict__ Wt2,
    const float* __restrict__ b0, const float* __restrict__ b1, const float* __restrict__ b2,
    unsigned char* __restrict__ C0, unsigned char* __restrict__ C1, unsigned char* __restrict__ C2,
    int M, int N)
{
    const unsigned short* Wt = (blockIdx.z == 0) ? Wt0 : (blockIdx.z == 1) ? Wt1 : Wt2;
    const float* bias        = (blockIdx.z == 0) ? b0  : (blockIdx.z == 1) ? b1  : b2;
    unsigned char* Cb        = (blockIdx.z == 0) ? C0  : (blockIdx.z == 1) ? C1  : C2;

    __shared__ unsigned short As[64][136];
    __shared__ unsigned short Bs[64][136];
    const int tid  = threadIdx.x;
    const int w    = tid >> 6;
    const int lane = tid & 63;
    const int quad = lane >> 4;
    const int l15  = lane & 15;
    const int m0 = blockIdx.x * 64;
    const int n0 = blockIdx.y * 64;

    floatx4 acc[4];
    #pragma unroll
    for (int t = 0; t < 4; ++t) acc[t] = (floatx4)0.0f;

    for (int kc = 0; kc < 256; kc += 128) {
        __syncthreads();
        #pragma unroll
        for (int idx = tid; idx < 1024; idx += 256) {
            int r = idx >> 4, g = idx & 15;
            *(short8*)&As[r][g * 8] = *(const short8*)&A[(size_t)(m0 + r) * 256 + kc + g * 8];
            *(short8*)&Bs[r][g * 8] = *(const short8*)&Wt[(size_t)(n0 + r) * 256 + kc + g * 8];
        }
        __syncthreads();
        #pragma unroll
        for (int s = 0; s < 4; ++s) {
            short8 a = *(const short8*)&As[w * 16 + l15][s * 32 + quad * 8];
            #pragma unroll
            for (int t = 0; t < 4; ++t) {
                short8 bfr = *(const short8*)&Bs[t * 16 + l15][s * 32 + quad * 8];
                acc[t] = MFMA16(a, bfr, acc[t]);
            }
        }
    }

    #pragma unroll
    for (int t = 0; t < 4; ++t) {
        int n = n0 + t * 16 + l15;
        float bs = bias[n];
        #pragma unroll
        for (int r = 0; r < 4; ++r) {
            int m = m0 + w * 16 + quad * 4 + r;
            Cb[(size_t)m * N + n] = f2fp8(acc[t][r] + bs);
        }
    }
}

// ---------------- flash attention v7: software-pipelined K-loop ----------------
// Round-9 model: serial per-iter chain load(~500)->QK->exp->LDS->PV = ~5.2K cyc/slot,
// MFMA only 24% (matches MfmaUtil). v7 double-buffers the register staging (bufA/bufB)
// and issues iteration t+1's 32 loads at the TOP of iteration t (sched_barrier-pinned),
// giving each batch a full iteration (~1.3K cyc) of lead -> latency hidden; cost
// collapses toward the MFMA-pipe floor (2 waves x 640 cyc/iter-slot ~ 34 us).
// Structure otherwise = v6: fp8 everywhere, 512 blocks, XCD pinning, 2-way merge.

__global__ __launch_bounds__(256, 2) void flash_attn(
    const unsigned char* __restrict__ qg,      // fp8 Q row-major [b][n][256]
    const unsigned char* __restrict__ kp,      // fragment-packed fp8 K
    const unsigned char* __restrict__ vp,      // fragment-packed fp8 V
    const unsigned short* __restrict__ xb,     // bf16 x for residual
    const float* __restrict__ gamma,
    float* __restrict__ out)
{
    __shared__ unsigned char Ps[4][16][48];    // per-wave fp8 P tile: 16 rows x 32 keys
    __shared__ float Mb[32][260];              // merge buffer: 32 rows x 256 f
    __shared__ float Ml[32];                   // merged row-sums

    const int tid  = threadIdx.x;
    const int w    = tid >> 6;
    const int lane = tid & 63;
    const int quad = lane >> 4;
    const int l15  = lane & 15;
    const int rw   = w & 1;
    const int kh   = w >> 1;
    const int blk  = blockIdx.x;
    const int b    = (blk & 7) >> 1;              // XCD-pinned batch
    const int rt   = (blk >> 3) * 2 + (blk & 1);  // row-tile 0..127
    const int row0 = rt * 32 + rw * 16;

    // Q fragments (A-layout: m = lane&15, k = quad*8+j), 8 B/lane each
    const size_t baseQ = ((size_t)b * 4096 + row0 + l15) * 256;
    long qf[8];
    #pragma unroll
    for (int s = 0; s < 8; ++s)
        qf[s] = *(const long*)&qg[baseQ + s * 32 + quad * 8];

    const long ones8 = 0x3838383838383838L;    // e4m3 1.0 x8

    floatx4 ctx[16];
    #pragma unroll
    for (int i = 0; i < 16; ++i) ctx[i] = (floatx4)0.0f;
    floatx4 lacc = (floatx4)0.0f;

    // per-iter bases: iter t covers keys kh*2048 + t*32; both packed layouts put one
    // 64-key tile in 16 KB, one 32-key half-tile in 8 KB -> byte offset t*8192.
    const unsigned char* kbase = kp + (size_t)b * 1048576 + (size_t)kh * 524288 + (size_t)lane * 8;
    const unsigned char* vbase = vp + (size_t)b * 1048576 + (size_t)kh * 524288 + (size_t)lane * 8;

    long kA[16], vA[16], kB[16], vB[16];

    // prologue: load iter 0 into buffer A
    #pragma unroll
    for (int s = 0; s < 16; ++s) kA[s] = *(const long*)&kbase[(size_t)s * 512];
    #pragma unroll
    for (int i = 0; i < 16; ++i) vA[i] = *(const long*)&vbase[(size_t)i * 512];

#define FA_STEP(KR, VR)                                                          \
    {                                                                            \
        floatx4 sac0 = (floatx4)0.0f, sac1 = (floatx4)0.0f;                      \
        _Pragma("unroll")                                                        \
        for (int s = 0; s < 8; ++s) sac0 = MFMA8(qf[s], KR[s], sac0);            \
        _Pragma("unroll")                                                        \
        for (int s = 0; s < 8; ++s) sac1 = MFMA8(qf[s], KR[8 + s], sac1);        \
        _Pragma("unroll")                                                        \
        for (int r = 0; r < 4; ++r) {                                            \
            Ps[w][quad * 4 + r][l15]      = f2fp8(__expf(sac0[r]));              \
            Ps[w][quad * 4 + r][16 + l15] = f2fp8(__expf(sac1[r]));              \
        }                                                                        \
        long ap = *(const long*)&Ps[w][l15][quad * 8];                           \
        lacc = MFMA8(ap, ones8, lacc);                                           \
        _Pragma("unroll")                                                        \
        for (int fi = 0; fi < 16; ++fi) ctx[fi] = MFMA8(ap, VR[fi], ctx[fi]);    \
    }

    for (int tt = 0; tt < 32; ++tt) {
        const size_t o1 = (size_t)(2 * tt + 1) * 8192;
        const size_t o2 = (size_t)((2 * tt + 2) & 63) * 8192;   // wraps to 0 on last pair (harmless re-read)

        // prefetch iter 2tt+1 into B, pinned above the consumption of A
        #pragma unroll
        for (int s = 0; s < 16; ++s) kB[s] = *(const long*)&kbase[o1 + (size_t)s * 512];
        #pragma unroll
        for (int i = 0; i < 16; ++i) vB[i] = *(const long*)&vbase[o1 + (size_t)i * 512];
        __builtin_amdgcn_sched_barrier(0);

        FA_STEP(kA, vA)

        // prefetch iter 2tt+2 into A, pinned above the consumption of B
        #pragma unroll
        for (int s = 0; s < 16; ++s) kA[s] = *(const long*)&kbase[o2 + (size_t)s * 512];
        #pragma unroll
        for (int i = 0; i < 16; ++i) vA[i] = *(const long*)&vbase[o2 + (size_t)i * 512];
        __builtin_amdgcn_sched_barrier(0);

        FA_STEP(kB, vB)
    }
#undef FA_STEP

    // ---- merge the two key-halves (plain sums; maxless softmax) ----
    __syncthreads();
    if (kh == 1) {
        #pragma unroll
        for (int fi = 0; fi < 16; ++fi) {
            #pragma unroll
            for (int r = 0; r < 4; ++r)
                Mb[rw * 16 + quad * 4 + r][fi * 16 + l15] = ctx[fi][r];
        }
        if (l15 == 0) {
            #pragma unroll
            for (int r = 0; r < 4; ++r) Ml[rw * 16 + quad * 4 + r] = lacc[r];
        }
    }
    __syncthreads();
    if (kh == 0) {
        #pragma unroll
        for (int fi = 0; fi < 16; ++fi) {
            #pragma unroll
            for (int r = 0; r < 4; ++r)
                Mb[rw * 16 + quad * 4 + r][fi * 16 + l15] += ctx[fi][r];
        }
        if (l15 == 0) {
            #pragma unroll
            for (int r = 0; r < 4; ++r) Ml[rw * 16 + quad * 4 + r] += lacc[r];
        }
    }
    __syncthreads();

    // ---- cooperative epilogue: out = gamma * Mb / Ml + x (coalesced float4) ----
    const float g = gamma[0];
    const int row = tid >> 3;          // 0..31
    const int c0  = (tid & 7) * 32;    // 0..224
    const float rl = 1.0f / Ml[row];
    const size_t o = ((size_t)b * 4096 + rt * 32 + row) * 256 + c0;
    #pragma unroll
    for (int j = 0; j < 4; ++j) {
        short8 xv = *(const short8*)&xb[o + j * 8];
        float res[8];
        #pragma unroll
        for (int i = 0; i < 8; ++i)
            res[i] = g * Mb[row][c0 + j * 8 + i] * rl + bf2f((unsigned short)xv[i]);
        *(float4*)&out[o + j * 8]     = *(float4*)&res[0];
        *(float4*)&out[o + j * 8 + 4] = *(float4*)&res[4];
    }
}

// ---------------- host launch ----------------
// Workspace — total ~24.5 MB (well under the proven ~42.7 MB envelope):
//   0    q8 4 MB | 4M k8 4 MB (packed in-place) | 8M v8 4 MB (packed in-place)
//   12M  x_b bf16 8 MB | 20M in_b 4 MB | 24M Wt_p/q/k/v 448 KB

extern "C" void kernel_launch(void* const* d_in, const int* in_sizes, int n_in,
                              void* d_out, int out_size, void* d_ws, size_t ws_size,
                              hipStream_t stream)
{
    const float* inp   = (const float*)d_in[0];
    const float* Wp    = (const float*)d_in[1];
    const float* bp    = (const float*)d_in[2];
    const float* Wq    = (const float*)d_in[3];
    const float* bq    = (const float*)d_in[4];
    const float* Wk    = (const float*)d_in[5];
    const float* bk    = (const float*)d_in[6];
    const float* Wv    = (const float*)d_in[7];
    const float* bv    = (const float*)d_in[8];
    const float* gamma = (const float*)d_in[9];
    float* out = (float*)d_out;

    char* ws = (char*)d_ws;
    unsigned char*  q8    = (unsigned char*)(ws + 0);
    unsigned char*  k8    = (unsigned char*)(ws + 4194304);
    unsigned char*  v8    = (unsigned char*)(ws + 8388608);
    unsigned short* x_b   = (unsigned short*)(ws + 12582912);
    unsigned short* in_b  = (unsigned short*)(ws + 20971520);
    unsigned short* Wt_p  = (unsigned short*)(ws + 25165824);
    unsigned short* Wt_q  = (unsigned short*)(ws + 25231360);
    unsigned short* Wt_k  = (unsigned short*)(ws + 25362432);
    unsigned short* Wt_v  = (unsigned short*)(ws + 25493504);

    cast_f32_bf16<<<2048, 256, 0, stream>>>(inp, in_b, 2097152 / 4);
    transpose_cast<<<128, 256, 0, stream>>>(Wp, Wt_p, 128, 256);
    transpose_cast<<<256, 256, 0, stream>>>(Wq, Wt_q, 256, 256);
    transpose_cast<<<256, 256, 0, stream>>>(Wk, Wt_k, 256, 256);
    transpose_cast<<<256, 256, 0, stream>>>(Wv, Wt_v, 256, 256);

    gemm_bias<128><<<dim3(256, 4), 256, 0, stream>>>(in_b, Wt_p, bp, x_b, 16384, 256);
    gemm_qkv<<<dim3(256, 4, 3), 256, 0, stream>>>(x_b, Wt_q, Wt_k, Wt_v, bq, bk, bv,
                                                  q8, k8, v8, 16384, 256);
    pack_k8<<<dim3(64, 4), 256, 0, stream>>>(k8);
    pack_v8<<<dim3(64, 4), 256, 0, stream>>>(v8);

    flash_attn<<<512, 256, 0, stream>>>(q8, k8, v8, x_b, gamma, out);
}

// Round 12
// 203.063 us; speedup vs baseline: 1.2217x; 1.2217x over previous
//
#include <hip/hip_runtime.h>
#include <hip/hip_bf16.h>
#include <stdint.h>

typedef __attribute__((ext_vector_type(8))) short short8;
typedef __attribute__((ext_vector_type(4))) float floatx4;

#define DEVI __device__ __forceinline__
#define MFMA16(a, b, c) __builtin_amdgcn_mfma_f32_16x16x32_bf16((a), (b), (c), 0, 0, 0)
#define MFMA8(a, b, c)  __builtin_amdgcn_mfma_f32_16x16x32_fp8_fp8((a), (b), (c), 0, 0, 0)

typedef __attribute__((address_space(3))) unsigned int lds_u32;
typedef __attribute__((address_space(1))) const unsigned int glb_u32;
// async 16B/lane DMA global->LDS: lds dest = wave-uniform base + lane*16 (contiguous 1KB/wave)
#define GLOAD_LDS16(g, l) __builtin_amdgcn_global_load_lds((glb_u32*)(g), (lds_u32*)(l), 16, 0, 0)

DEVI unsigned short f2bf(float x) {
    union { float f; unsigned int u; } v; v.f = x;
    unsigned int r = v.u + 0x7FFFu + ((v.u >> 16) & 1u);
    return (unsigned short)(r >> 16);
}
DEVI float bf2f(unsigned short h) {
    union { unsigned int u; float f; } v; v.u = ((unsigned int)h) << 16;
    return v.f;
}
DEVI unsigned char f2fp8(float x) {   // OCP e4m3 via HW converter
    int c = __builtin_amdgcn_cvt_pk_fp8_f32(x, x, 0, false);
    return (unsigned char)(c & 0xFF);
}

// ---------------- cast / transpose prep kernels ----------------

__global__ void cast_f32_bf16(const float* __restrict__ in, unsigned short* __restrict__ out, int n4) {
    int i = blockIdx.x * blockDim.x + threadIdx.x;
    if (i < n4) {
        float4 v = ((const float4*)in)[i];
        ushort4 o;
        o.x = f2bf(v.x); o.y = f2bf(v.y); o.z = f2bf(v.z); o.w = f2bf(v.w);
        ((ushort4*)out)[i] = o;
    }
}

// Wt[n][k] = bf16(W[k][n]);  W is [K][N] row-major
__global__ void transpose_cast(const float* __restrict__ W, unsigned short* __restrict__ Wt, int K, int N) {
    int idx = blockIdx.x * blockDim.x + threadIdx.x;
    if (idx < K * N) {
        int k = idx / N, n = idx % N;
        Wt[n * K + k] = f2bf(W[idx]);
    }
}

// ---------------- in-place fp8 fragment packing ----------------
// K pack (fp8): frag (n16, s): lane l holds K[n16*16+(l&15)][s*32+(l>>4)*8+j], j=0..7,
// stored at byte offset ((n16*8+s)*512 + l*8). 64-key tile spans 16 KB -> in-place via LDS.
__global__ __launch_bounds__(256) void pack_k8(unsigned char* __restrict__ kb) {
    __shared__ unsigned char T[64][272];
    const int b = blockIdx.y, k0 = blockIdx.x * 64;
    unsigned char* base = kb + (size_t)b * 1048576 + (size_t)k0 * 256;
    const int tid = threadIdx.x;
    #pragma unroll
    for (int it = 0; it < 4; ++it) {
        int idx = tid + it * 256;            // 0..1023 x 16B
        int row = idx >> 4, col = (idx & 15) * 16;
        *(int4*)&T[row][col] = *(const int4*)&base[(size_t)row * 256 + col];
    }
    __syncthreads();
    const int w = tid >> 6, lane = tid & 63, l15 = lane & 15, quad = lane >> 4;
    #pragma unroll
    for (int s = 0; s < 8; ++s) {
        long o = *(const long*)&T[w * 16 + l15][s * 32 + quad * 8];
        *(long*)&base[(size_t)(w * 8 + s) * 512 + lane * 8] = o;
    }
}

// V pack (fp8): frag (nc, f16): lane l holds V[nc*32+(l>>4)*8+j][f16*16+(l&15)],
// stored at ((nc*16+f16)*512 + l*8). Same in-place property per 64-key tile.
__global__ __launch_bounds__(256) void pack_v8(unsigned char* __restrict__ vb) {
    __shared__ unsigned char T[64][272];
    const int b = blockIdx.y, k0 = blockIdx.x * 64;
    unsigned char* base = vb + (size_t)b * 1048576 + (size_t)k0 * 256;
    const int tid = threadIdx.x;
    #pragma unroll
    for (int it = 0; it < 4; ++it) {
        int idx = tid + it * 256;
        int row = idx >> 4, col = (idx & 15) * 16;
        *(int4*)&T[row][col] = *(const int4*)&base[(size_t)row * 256 + col];
    }
    __syncthreads();
    const int w = tid >> 6, lane = tid & 63, l15 = lane & 15, quad = lane >> 4;
    const int ncl = w >> 1;
    #pragma unroll
    for (int ff = 0; ff < 8; ++ff) {
        int f16 = (w & 1) * 8 + ff;
        union { unsigned char bts[8]; long l; } o;
        #pragma unroll
        for (int j = 0; j < 8; ++j)
            o.bts[j] = T[ncl * 32 + quad * 8 + j][f16 * 16 + l15];
        *(long*)&base[(size_t)(ncl * 16 + f16) * 512 + lane * 8] = o.l;
    }
}

// ---------------- bf16 MFMA GEMM: C = A @ Wt^T + bias (bf16 out) ----------------

template<int K>
__global__ __launch_bounds__(256) void gemm_bias(
    const unsigned short* __restrict__ A,
    const unsigned short* __restrict__ Wt,
    const float* __restrict__ bias,
    unsigned short* __restrict__ Cb,
    int M, int N)
{
    __shared__ unsigned short As[64][136];
    __shared__ unsigned short Bs[64][136];
    const int tid  = threadIdx.x;
    const int w    = tid >> 6;
    const int lane = tid & 63;
    const int quad = lane >> 4;
    const int l15  = lane & 15;
    const int m0 = blockIdx.x * 64;
    const int n0 = blockIdx.y * 64;

    floatx4 acc[4];
    #pragma unroll
    for (int t = 0; t < 4; ++t) acc[t] = (floatx4)0.0f;

    for (int kc = 0; kc < K; kc += 128) {
        __syncthreads();
        #pragma unroll
        for (int idx = tid; idx < 1024; idx += 256) {
            int r = idx >> 4, g = idx & 15;
            *(short8*)&As[r][g * 8] = *(const short8*)&A[(size_t)(m0 + r) * K + kc + g * 8];
            *(short8*)&Bs[r][g * 8] = *(const short8*)&Wt[(size_t)(n0 + r) * K + kc + g * 8];
        }
        __syncthreads();
        #pragma unroll
        for (int s = 0; s < 4; ++s) {
            short8 a = *(const short8*)&As[w * 16 + l15][s * 32 + quad * 8];
            #pragma unroll
            for (int t = 0; t < 4; ++t) {
                short8 bfr = *(const short8*)&Bs[t * 16 + l15][s * 32 + quad * 8];
                acc[t] = MFMA16(a, bfr, acc[t]);
            }
        }
    }

    #pragma unroll
    for (int t = 0; t < 4; ++t) {
        int n = n0 + t * 16 + l15;
        float bs = bias[n];
        #pragma unroll
        for (int r = 0; r < 4; ++r) {
            int m = m0 + w * 16 + quad * 4 + r;
            Cb[(size_t)m * N + n] = f2bf(acc[t][r] + bs);
        }
    }
}

// Fused Q/K/V GEMM with fp8 output: blockIdx.z selects weight/bias/output.
__global__ __launch_bounds__(256) void gemm_qkv(
    const unsigned short* __restrict__ A,
    const unsigned short* __restrict__ Wt0, const unsigned short* __restrict__ Wt1, const unsigned short* __restrict__ Wt2,
    const float* __restrict__ b0, const float* __restrict__ b1, const float* __restrict__ b2,
    unsigned char* __restrict__ C0, unsigned char* __restrict__ C1, unsigned char* __restrict__ C2,
    int M, int N)
{
    const unsigned short* Wt = (blockIdx.z == 0) ? Wt0 : (blockIdx.z == 1) ? Wt1 : Wt2;
    const float* bias        = (blockIdx.z == 0) ? b0  : (blockIdx.z == 1) ? b1  : b2;
    unsigned char* Cb        = (blockIdx.z == 0) ? C0  : (blockIdx.z == 1) ? C1  : C2;

    __shared__ unsigned short As[64][136];
    __shared__ unsigned short Bs[64][136];
    const int tid  = threadIdx.x;
    const int w    = tid >> 6;
    const int lane = tid & 63;
    const int quad = lane >> 4;
    const int l15  = lane & 15;
    const int m0 = blockIdx.x * 64;
    const int n0 = blockIdx.y * 64;

    floatx4 acc[4];
    #pragma unroll
    for (int t = 0; t < 4; ++t) acc[t] = (floatx4)0.0f;

    for (int kc = 0; kc < 256; kc += 128) {
        __syncthreads();
        #pragma unroll
        for (int idx = tid; idx < 1024; idx += 256) {
            int r = idx >> 4, g = idx & 15;
            *(short8*)&As[r][g * 8] = *(const short8*)&A[(size_t)(m0 + r) * 256 + kc + g * 8];
            *(short8*)&Bs[r][g * 8] = *(const short8*)&Wt[(size_t)(n0 + r) * 256 + kc + g * 8];
        }
        __syncthreads();
        #pragma unroll
        for (int s = 0; s < 4; ++s) {
            short8 a = *(const short8*)&As[w * 16 + l15][s * 32 + quad * 8];
            #pragma unroll
            for (int t = 0; t < 4; ++t) {
                short8 bfr = *(const short8*)&Bs[t * 16 + l15][s * 32 + quad * 8];
                acc[t] = MFMA16(a, bfr, acc[t]);
            }
        }
    }

    #pragma unroll
    for (int t = 0; t < 4; ++t) {
        int n = n0 + t * 16 + l15;
        float bs = bias[n];
        #pragma unroll
        for (int r = 0; r < 4; ++r) {
            int m = m0 + w * 16 + quad * 4 + r;
            Cb[(size_t)m * N + n] = f2fp8(acc[t][r] + bs);
        }
    }
}

// ---------------- flash attention v8.1: async LDS double-buffer (overlay fix) ----------------
// v8 failed correctness: Mb overlay needs 32*260*4 = 33,280 B but KV[0] is 32,768 B;
// row 31 spilled into KV[1][0..512) where Ml lived -> denominators clobbered (absmax
// 0.75). v8.1 places Ml AFTER Mb inside the full 64 KB KV region (offset 33,280;
// total 33,408 <= 65,536). Pipeline unchanged: global_load_lds DMA stages the next
// 32-key tile's K+V (32 KB) into buf^1 while compute consumes buf; one barrier/iter
// drains DMAs issued a full iteration earlier; fragments read via ds_read_b64.

__global__ __launch_bounds__(256, 2) void flash_attn(
    const unsigned char* __restrict__ qg,      // fp8 Q row-major [b][n][256]
    const unsigned char* __restrict__ kp,      // fragment-packed fp8 K
    const unsigned char* __restrict__ vp,      // fragment-packed fp8 V
    const unsigned short* __restrict__ xb,     // bf16 x for residual
    const float* __restrict__ gamma,
    float* __restrict__ out)
{
    __shared__ __align__(16) unsigned char KV[2][32768]; // [buf][kh0: K8K,V8K | kh1: K8K,V8K]
    __shared__ unsigned char Ps[4][16][48];              // per-wave fp8 P tile
    // merge buffers overlay KV after the K-loop: Mb 33,280 B then Ml 128 B (<= 65,536)
    float* MbF = (float*)&KV[0][0];                      // Mb[r][c] = MbF[r*260+c]
    float* Ml  = MbF + 32 * 260;                         // byte offset 33,280 - past Mb

    const int tid  = threadIdx.x;
    const int w    = tid >> 6;
    const int lane = tid & 63;
    const int quad = lane >> 4;
    const int l15  = lane & 15;
    const int rw   = w & 1;
    const int kh   = w >> 1;
    const int blk  = blockIdx.x;
    const int b    = (blk & 7) >> 1;              // XCD-pinned batch
    const int rt   = (blk >> 3) * 2 + (blk & 1);  // row-tile 0..127
    const int row0 = rt * 32 + rw * 16;

    // Q fragments (A-layout: m = lane&15, k = quad*8+j), 8 B/lane each
    const size_t baseQ = ((size_t)b * 4096 + row0 + l15) * 256;
    long qf[8];
    #pragma unroll
    for (int s = 0; s < 8; ++s)
        qf[s] = *(const long*)&qg[baseQ + s * 32 + quad * 8];

    const long ones8 = 0x3838383838383838L;    // e4m3 1.0 x8

    floatx4 ctx[16];
    #pragma unroll
    for (int i = 0; i < 16; ++i) ctx[i] = (floatx4)0.0f;
    floatx4 lacc = (floatx4)0.0f;

    const unsigned char* kb_all = kp + (size_t)b * 1048576;
    const unsigned char* vb_all = vp + (size_t)b * 1048576;

    // stage(t -> buf): 32 KB = 32 x 1KB chunks; wave w DMAs chunks c = p*4+w.
    // chunk map: c>>4 = kh, (c>>3)&1 = K/V, (c&7)*1024 = offset within the 8 KB half.
    // Packed layouts are byte-contiguous per (kh, t): offset kh*524288 + t*8192.
#define FA_STAGE(T, BUF)                                                             \
    {                                                                                \
        _Pragma("unroll")                                                            \
        for (int p = 0; p < 8; ++p) {                                                \
            const int c    = p * 4 + w;                                              \
            const int ckh  = c >> 4;                                                 \
            const int csel = (c >> 3) & 1;                                           \
            const int coff = (c & 7) * 1024;                                         \
            const unsigned char* src = (csel ? vb_all : kb_all)                      \
                + (size_t)ckh * 524288 + (size_t)(T) * 8192 + coff + lane * 16;      \
            GLOAD_LDS16(src, &KV[BUF][ckh * 16384 + csel * 8192 + coff]);            \
        }                                                                            \
    }

    FA_STAGE(0, 0)   // prologue

    for (int t = 0; t < 64; ++t) {
        const int buf = t & 1;
        __syncthreads();                 // drains vmcnt -> staging(t) complete & visible
        if (t < 63) FA_STAGE(t + 1, buf ^ 1)

        const unsigned char* kc = &KV[buf][kh * 16384];
        const unsigned char* vc = &KV[buf][kh * 16384 + 8192];

        // ---- S = Q K^T over 32 keys (K frags via ds_read_b64, conflict-free) ----
        floatx4 sac0 = (floatx4)0.0f, sac1 = (floatx4)0.0f;
        #pragma unroll
        for (int s = 0; s < 8; ++s) {
            long kf0 = *(const long*)&kc[(size_t)s * 512 + lane * 8];
            long kf1 = *(const long*)&kc[(size_t)(8 + s) * 512 + lane * 8];
            sac0 = MFMA8(qf[s], kf0, sac0);
            sac1 = MFMA8(qf[s], kf1, sac1);
        }

        // ---- p = exp(s) -> fp8 -> per-wave Ps (C-layout -> A-layout round trip) ----
        #pragma unroll
        for (int r = 0; r < 4; ++r) {
            Ps[w][quad * 4 + r][l15]      = f2fp8(__expf(sac0[r]));
            Ps[w][quad * 4 + r][16 + l15] = f2fp8(__expf(sac1[r]));
        }

        // ---- PV partial + row-sum via ones-MFMA (V frags from LDS) ----
        long ap = *(const long*)&Ps[w][l15][quad * 8];
        lacc = MFMA8(ap, ones8, lacc);
        #pragma unroll
        for (int fi = 0; fi < 16; ++fi) {
            long vfrag = *(const long*)&vc[(size_t)fi * 512 + lane * 8];
            ctx[fi] = MFMA8(ap, vfrag, ctx[fi]);
        }
    }
#undef FA_STAGE

    // ---- merge the two key-halves (plain sums; maxless softmax); Mb/Ml overlay KV ----
    __syncthreads();
    if (kh == 1) {
        #pragma unroll
        for (int fi = 0; fi < 16; ++fi) {
            #pragma unroll
            for (int r = 0; r < 4; ++r)
                MbF[(rw * 16 + quad * 4 + r) * 260 + fi * 16 + l15] = ctx[fi][r];
        }
        if (l15 == 0) {
            #pragma unroll
            for (int r = 0; r < 4; ++r) Ml[rw * 16 + quad * 4 + r] = lacc[r];
        }
    }
    __syncthreads();
    if (kh == 0) {
        #pragma unroll
        for (int fi = 0; fi < 16; ++fi) {
            #pragma unroll
            for (int r = 0; r < 4; ++r)
                MbF[(rw * 16 + quad * 4 + r) * 260 + fi * 16 + l15] += ctx[fi][r];
        }
        if (l15 == 0) {
            #pragma unroll
            for (int r = 0; r < 4; ++r) Ml[rw * 16 + quad * 4 + r] += lacc[r];
        }
    }
    __syncthreads();

    // ---- cooperative epilogue: out = gamma * Mb / Ml + x (coalesced float4) ----
    const float g = gamma[0];
    const int row = tid >> 3;          // 0..31
    const int c0  = (tid & 7) * 32;    // 0..224
    const float rl = 1.0f / Ml[row];
    const size_t o = ((size_t)b * 4096 + rt * 32 + row) * 256 + c0;
    #pragma unroll
    for (int j = 0; j < 4; ++j) {
        short8 xv = *(const short8*)&xb[o + j * 8];
        float res[8];
        #pragma unroll
        for (int i = 0; i < 8; ++i)
            res[i] = g * MbF[row * 260 + c0 + j * 8 + i] * rl + bf2f((unsigned short)xv[i]);
        *(float4*)&out[o + j * 8]     = *(float4*)&res[0];
        *(float4*)&out[o + j * 8 + 4] = *(float4*)&res[4];
    }
}

// ---------------- host launch ----------------
// Workspace — total ~24.5 MB (well under the proven ~42.7 MB envelope):
//   0    q8 4 MB | 4M k8 4 MB (packed in-place) | 8M v8 4 MB (packed in-place)
//   12M  x_b bf16 8 MB | 20M in_b 4 MB | 24M Wt_p/q/k/v 448 KB

extern "C" void kernel_launch(void* const* d_in, const int* in_sizes, int n_in,
                              void* d_out, int out_size, void* d_ws, size_t ws_size,
                              hipStream_t stream)
{
    const float* inp   = (const float*)d_in[0];
    const float* Wp    = (const float*)d_in[1];
    const float* bp    = (const float*)d_in[2];
    const float* Wq    = (const float*)d_in[3];
    const float* bq    = (const float*)d_in[4];
    const float* Wk    = (const float*)d_in[5];
    const float* bk    = (const float*)d_in[6];
    const float* Wv    = (const float*)d_in[7];
    const float* bv    = (const float*)d_in[8];
    const float* gamma = (const float*)d_in[9];
    float* out = (float*)d_out;

    char* ws = (char*)d_ws;
    unsigned char*  q8    = (unsigned char*)(ws + 0);
    unsigned char*  k8    = (unsigned char*)(ws + 4194304);
    unsigned char*  v8    = (unsigned char*)(ws + 8388608);
    unsigned short* x_b   = (unsigned short*)(ws + 12582912);
    unsigned short* in_b  = (unsigned short*)(ws + 20971520);
    unsigned short* Wt_p  = (unsigned short*)(ws + 25165824);
    unsigned short* Wt_q  = (unsigned short*)(ws + 25231360);
    unsigned short* Wt_k  = (unsigned short*)(ws + 25362432);
    unsigned short* Wt_v  = (unsigned short*)(ws + 25493504);

    cast_f32_bf16<<<2048, 256, 0, stream>>>(inp, in_b, 2097152 / 4);
    transpose_cast<<<128, 256, 0, stream>>>(Wp, Wt_p, 128, 256);
    transpose_cast<<<256, 256, 0, stream>>>(Wq, Wt_q, 256, 256);
    transpose_cast<<<256, 256, 0, stream>>>(Wk, Wt_k, 256, 256);
    transpose_cast<<<256, 256, 0, stream>>>(Wv, Wt_v, 256, 256);

    gemm_bias<128><<<dim3(256, 4), 256, 0, stream>>>(in_b, Wt_p, bp, x_b, 16384, 256);
    gemm_qkv<<<dim3(256, 4, 3), 256, 0, stream>>>(x_b, Wt_q, Wt_k, Wt_v, bq, bk, bv,
                                                  q8, k8, v8, 16384, 256);
    pack_k8<<<dim3(64, 4), 256, 0, stream>>>(k8);
    pack_v8<<<dim3(64, 4), 256, 0, stream>>>(v8);

    flash_attn<<<512, 256, 0, stream>>>(q8, k8, v8, x_b, gamma, out);
}